// Round 7
// baseline (306.548 us; speedup 1.0000x reference)
//
#include <hip/hip_runtime.h>
#include <hip/hip_bf16.h>
#include <cstddef>
#include <cstdint>

// Problem constants: B=4, T=2048, C=1024, NH=16, hs=64, M = B*T = 8192
#define B_DIM 4
#define T_DIM 2048
#define C_DIM 1024
#define NHEAD 16
#define HS    64
#define QKV_LD 3072   // fused QKV row stride (3*C)

typedef __attribute__((ext_vector_type(8))) short short8;   // 8 bf16 (MFMA A/B frag)
typedef __attribute__((ext_vector_type(4))) float f32x4;    // MFMA C/D frag

__device__ __forceinline__ short f2bf(float x) {
    __hip_bfloat16 b = __float2bfloat16(x);   // RNE
    return *reinterpret_cast<short*>(&b);
}

// async global->LDS, 16B per lane; LDS dest is wave-uniform base + lane*16.
__device__ __forceinline__ void load_lds16(const void* g, void* l) {
    __builtin_amdgcn_global_load_lds(
        (const __attribute__((address_space(1))) void*)(g),
        (__attribute__((address_space(3))) void*)(l),
        16, 0, 0);
}

// ---------------------------------------------------------------------------
// cast fp32 -> bf16, 8 elements/thread
// ---------------------------------------------------------------------------
__global__ __launch_bounds__(256) void cast_bf16(
    const float* __restrict__ in, short* __restrict__ out, int n8)
{
    int i = blockIdx.x * 256 + threadIdx.x;
    if (i >= n8) return;
    const float4* p = (const float4*)in + (size_t)i * 2;
    float4 a = p[0], b = p[1];
    short8 o;
    o[0]=f2bf(a.x); o[1]=f2bf(a.y); o[2]=f2bf(a.z); o[3]=f2bf(a.w);
    o[4]=f2bf(b.x); o[5]=f2bf(b.y); o[6]=f2bf(b.z); o[7]=f2bf(b.w);
    *((short8*)out + i) = o;
}

// cast 4 weight matrices in one launch (blockIdx.y selects source)
__global__ __launch_bounds__(256) void cast_w4(
    const float* __restrict__ w0, const float* __restrict__ w1,
    const float* __restrict__ w2, const float* __restrict__ w3,
    short* __restrict__ o0, short* __restrict__ o1,
    short* __restrict__ o2, short* __restrict__ o3, int n8)
{
    int i = blockIdx.x * 256 + threadIdx.x;
    if (i >= n8) return;
    const float* in; short* out;
    switch (blockIdx.y) {
        case 0: in = w0; out = o0; break;
        case 1: in = w1; out = o1; break;
        case 2: in = w2; out = o2; break;
        default: in = w3; out = o3; break;
    }
    const float4* p = (const float4*)in + (size_t)i * 2;
    float4 a = p[0], b = p[1];
    short8 o;
    o[0]=f2bf(a.x); o[1]=f2bf(a.y); o[2]=f2bf(a.z); o[3]=f2bf(a.w);
    o[4]=f2bf(b.x); o[5]=f2bf(b.y); o[6]=f2bf(b.z); o[7]=f2bf(b.w);
    *((short8*)out + i) = o;
}

// ---------------------------------------------------------------------------
// MFMA GEMM: C[M,N] = A[M,K] @ B[N,K]^T, bf16 in, fp32 accumulate.
// 128x128 tile, BK=32, 4 waves (2x2), 16x16x32 MFMA, global_load_lds w=16,
// XOR-swizzled LDS (chunk q of row m at slot m*4 + (q ^ ((m>>1)&3))).
// ---------------------------------------------------------------------------
#define BM 128
#define BN 128
#define BK 32

template<bool OUT_BF16>
__global__ __launch_bounds__(256) void gemm_bt_mfma(
    const short* __restrict__ A,
    const short* __restrict__ Bm,
    void* __restrict__ Cm,
    int M, int N, int K, float scale)
{
    __shared__ __align__(16) short smem[8192];   // As 8KB | Bs 8KB
    short* As = smem;
    short* Bs = smem + 4096;

    const int m0 = blockIdx.y * BM;
    const int n0 = blockIdx.x * BN;
    const int t    = threadIdx.x;
    const int w    = t >> 6;
    const int lane = t & 63;
    const int l16  = lane & 15;
    const int quad = lane >> 4;
    const int wm   = w >> 1;
    const int wn   = w & 1;

    const int mS0 = t >> 2;
    const int qS  = (t & 3) ^ ((t >> 3) & 3);
    const short* aG0 = A  + (size_t)(m0 + mS0)      * K + qS * 8;
    const short* aG1 = A  + (size_t)(m0 + mS0 + 64) * K + qS * 8;
    const short* bG0 = Bm + (size_t)(n0 + mS0)      * K + qS * 8;
    const short* bG1 = Bm + (size_t)(n0 + mS0 + 64) * K + qS * 8;
    short* aL0 = As + (size_t)(w * 64) * 8;
    short* aL1 = As + (size_t)(256 + w * 64) * 8;
    short* bL0 = Bs + (size_t)(w * 64) * 8;
    short* bL1 = Bs + (size_t)(256 + w * 64) * 8;

    int a_off[4], b_off[4];
    #pragma unroll
    for (int i = 0; i < 4; ++i) {
        int am = wm * 64 + i * 16 + l16;
        a_off[i] = (am * 4 + (quad ^ ((am >> 1) & 3))) * 8;
        int bn = wn * 64 + i * 16 + l16;
        b_off[i] = (bn * 4 + (quad ^ ((bn >> 1) & 3))) * 8;
    }

    f32x4 acc[4][4];
    const f32x4 zero4 = {0.f, 0.f, 0.f, 0.f};
    #pragma unroll
    for (int i = 0; i < 4; ++i)
        #pragma unroll
        for (int j = 0; j < 4; ++j) acc[i][j] = zero4;

    for (int k0 = 0; k0 < K; k0 += BK) {
        __syncthreads();
        load_lds16(aG0 + k0, aL0);
        load_lds16(aG1 + k0, aL1);
        load_lds16(bG0 + k0, bL0);
        load_lds16(bG1 + k0, bL1);
        __syncthreads();

        short8 af[4], bf[4];
        #pragma unroll
        for (int i = 0; i < 4; ++i) {
            af[i] = *(const short8*)(As + a_off[i]);
            bf[i] = *(const short8*)(Bs + b_off[i]);
        }
        #pragma unroll
        for (int i = 0; i < 4; ++i)
            #pragma unroll
            for (int j = 0; j < 4; ++j)
                acc[i][j] = __builtin_amdgcn_mfma_f32_16x16x32_bf16(
                    af[i], bf[j], acc[i][j], 0, 0, 0);
    }

    #pragma unroll
    for (int i = 0; i < 4; ++i) {
        const int row_base = m0 + wm * 64 + i * 16 + quad * 4;
        #pragma unroll
        for (int j = 0; j < 4; ++j) {
            const int col = n0 + wn * 64 + j * 16 + l16;
            #pragma unroll
            for (int r = 0; r < 4; ++r) {
                const size_t idx = (size_t)(row_base + r) * N + col;
                if (OUT_BF16) ((short*)Cm)[idx] = f2bf(acc[i][j][r] * scale);
                else          ((float*)Cm)[idx] = acc[i][j][r] * scale;
            }
        }
    }
}

// ---------------------------------------------------------------------------
// Transpose V: bf16 [B,T,srcLD] (head-interleaved cols) -> bf16 [B,NH,HS,T]
// ---------------------------------------------------------------------------
__global__ __launch_bounds__(256) void transpose_v(
    const short* __restrict__ Vb,
    short* __restrict__ Vt, int srcLD)
{
    const int t0 = blockIdx.x * 64;
    const int head = blockIdx.y;              // b*NHEAD + h
    const int b = head >> 4, h = head & 15;

    __shared__ short Ls[64][72];

    const int t = threadIdx.x;
    const int r = t >> 2;
    const int c = (t & 3) * 16;

    const short* src = Vb + ((size_t)(b * T_DIM) + t0 + r) * srcLD + h * HS + c;
    *(short8*)&Ls[r][c]     = *(const short8*)src;
    *(short8*)&Ls[r][c + 8] = *(const short8*)(src + 8);
    __syncthreads();

    short tmp[16];
    #pragma unroll
    for (int i = 0; i < 16; ++i) tmp[i] = Ls[c + i][r];
    short* dst = Vt + ((size_t)head * HS + r) * T_DIM + t0 + c;
    *(short8*)dst       = *(short8*)&tmp[0];
    *(short8*)(dst + 8) = *(short8*)&tmp[8];
}

// ---------------------------------------------------------------------------
// Flash attention v4: R6 dataflow, 8 waves/block (512 thr), QSUB=2.
// Block covers 256 q-rows (8 waves x 2 subtiles x 16 q); K/V staged once per
// key-tile and fragment-reused 2x per wave; 16 waves/CU (4/SIMD) for
// VALU<->MFMA overlap (R6's 2/SIMD couldn't hide the exp chain).
// Inner loop split into key-halves (hh) to keep live VGPRs ~118 <= 128.
// S^T trick + kappa K-row perm + no-max softmax: identical math to R6.
// ---------------------------------------------------------------------------
__global__ __launch_bounds__(512, 4) void attn_mfma4(
    const short* __restrict__ Qb,    // [B,T,QKV_LD], Q cols
    const short* __restrict__ Kb,    // [B,T,QKV_LD], K cols
    const short* __restrict__ Vt,    // [B*NH, HS, T]
    short* __restrict__ O)           // [B,T,C] bf16
{
    const int i0   = blockIdx.x * 256;
    const int head = blockIdx.y;
    const int b = head >> 4, h = head & 15;

    const int t    = threadIdx.x;
    const int w    = t >> 6;          // 0..7
    const int lane = t & 63;
    const int l16  = lane & 15;
    const int quad = lane >> 4;

    __shared__ short Ks[64][72];     // [perm key][dim]
    __shared__ short Vts[64][72];    // [dim][key]

    // Q fragments (B-operand): sub s covers q-rows i0 + s*128 + w*16 + l16
    short8 qf[2][2];
    #pragma unroll
    for (int sub = 0; sub < 2; ++sub) {
        const short* qrow = Qb
            + ((size_t)(b * T_DIM) + i0 + sub * 128 + w * 16 + l16) * QKV_LD + h * HS;
        qf[sub][0] = *(const short8*)(qrow + quad * 8);
        qf[sub][1] = *(const short8*)(qrow + 32 + quad * 8);
    }

    const f32x4 zero4 = {0.f, 0.f, 0.f, 0.f};
    f32x4 oacc[2][4];
    #pragma unroll
    for (int sub = 0; sub < 2; ++sub)
        #pragma unroll
        for (int dg = 0; dg < 4; ++dg) oacc[sub][dg] = zero4;
    float l_part[2] = {0.f, 0.f};

    // staging: 512 threads, each 1x16B chunk of K and of V per tile
    const int sr = t >> 3;                   // row 0..63
    const int sc = (t & 7) * 8;              // col chunk (shorts)
    // K LDS row permutation (R5-verified): [h|q:2|c|r:2] -> [h|c|q:2|r:2]
    const int krow = (sr & 32) | ((sr & 4) << 2) | ((sr & 24) >> 1) | (sr & 3);
    const short* kgbase = Kb + (size_t)(b * T_DIM) * QKV_LD + h * HS;
    const short* vgbase = Vt + ((size_t)head * HS + sr) * T_DIM;

    for (int j0 = 0; j0 < T_DIM; j0 += 64) {
        __syncthreads();                     // prev tile's LDS reads done
        *(short8*)&Ks[krow][sc] = *(const short8*)(kgbase + (size_t)(j0 + sr) * QKV_LD + sc);
        *(short8*)&Vts[sr][sc]  = *(const short8*)(vgbase + j0 + sc);
        __syncthreads();

        #pragma unroll
        for (int hh = 0; hh < 2; ++hh) {
            // K frags for tiles kt = 2hh, 2hh+1; V half-frags for this hh
            short8 ka[2][2], va[4];
            #pragma unroll
            for (int c = 0; c < 2; ++c) {
                const int kt = 2 * hh + c;
                ka[c][0] = *(const short8*)&Ks[kt * 16 + l16][quad * 8];
                ka[c][1] = *(const short8*)&Ks[kt * 16 + l16][32 + quad * 8];
            }
            #pragma unroll
            for (int dg = 0; dg < 4; ++dg)
                va[dg] = *(const short8*)&Vts[dg * 16 + l16][hh * 32 + quad * 8];

            #pragma unroll
            for (int sub = 0; sub < 2; ++sub) {
                f32x4 s[2];
                #pragma unroll
                for (int c = 0; c < 2; ++c) {
                    f32x4 acc = zero4;
                    acc = __builtin_amdgcn_mfma_f32_16x16x32_bf16(ka[c][0], qf[sub][0], acc, 0, 0, 0);
                    acc = __builtin_amdgcn_mfma_f32_16x16x32_bf16(ka[c][1], qf[sub][1], acc, 0, 0, 0);
                    s[c] = acc;
                }
                // exp2 with folded scale (0.125*log2e); pack pa slot j=4c+r
                short8 pa;
                float lp = l_part[sub];
                #pragma unroll
                for (int c = 0; c < 2; ++c)
                    #pragma unroll
                    for (int r = 0; r < 4; ++r) {
                        float p = exp2f(s[c][r] * 0.1803368801f);
                        lp += p;
                        pa[c * 4 + r] = f2bf(p);
                    }
                l_part[sub] = lp;
                #pragma unroll
                for (int dg = 0; dg < 4; ++dg)
                    oacc[sub][dg] = __builtin_amdgcn_mfma_f32_16x16x32_bf16(
                        pa, va[dg], oacc[sub][dg], 0, 0, 0);
            }
        }
    }

    #pragma unroll
    for (int sub = 0; sub < 2; ++sub) {
        float lp = l_part[sub];
        lp += __shfl_xor(lp, 16);
        lp += __shfl_xor(lp, 32);
        float linv[4];
        #pragma unroll
        for (int r = 0; r < 4; ++r)
            linv[r] = 1.0f / __shfl(lp, quad * 4 + r);

        #pragma unroll
        for (int r = 0; r < 4; ++r) {
            short* orow = O + ((size_t)(b * T_DIM) + i0 + sub * 128 + w * 16 + quad * 4 + r) * C_DIM + h * HS;
            #pragma unroll
            for (int dg = 0; dg < 4; ++dg)
                orow[dg * 16 + l16] = f2bf(oacc[sub][dg][r] * linv[r]);
        }
    }
}

// ---------------------------------------------------------------------------
// ws layout (bytes), NB = 2*M*C = 16.8MB, WB = 2*C*C = 2.1MB:
//   [0]      xb bf16 (reused as Ob after QKV gemm)
//   [NB]     QKVb bf16 [M,3C]  (3*NB)
//   [4NB]    Vt bf16 [B*NH,HS,T]
//   [5NB]    W3b (Wq|Wk|Wv rows, 3*WB) | Wob (WB)      total 92.4MB
// ---------------------------------------------------------------------------
extern "C" void kernel_launch(void* const* d_in, const int* in_sizes, int n_in,
                              void* d_out, int out_size, void* d_ws, size_t ws_size,
                              hipStream_t stream) {
    const float* x  = (const float*)d_in[0];
    const float* Wk = (const float*)d_in[1];
    const float* Wq = (const float*)d_in[2];
    const float* Wv = (const float*)d_in[3];
    const float* Wo = (const float*)d_in[4];
    float* out = (float*)d_out;

    const int M = B_DIM * T_DIM;                       // 8192
    const size_t NE = (size_t)M * C_DIM;               // 8.4M
    const size_t NB = 2 * NE;                          // bytes
    const size_t WB = (size_t)2 * C_DIM * C_DIM;
    const size_t WE = (size_t)C_DIM * C_DIM;           // elements

    char* ws = (char*)d_ws;
    short* xb   = (short*)(ws);
    short* Ob   = xb;                                  // reuse after QKV gemm
    short* QKVb = (short*)(ws + NB);
    short* Vtb  = (short*)(ws + 4 * NB);
    short* W3b  = (short*)(ws + 5 * NB);               // [3C, C] rows: Wq|Wk|Wv
    short* Wob  = (short*)(ws + 5 * NB + 3 * WB);

    // casts (2 launches)
    cast_bf16<<<(int)(NE / 8 / 256), 256, 0, stream>>>(x, xb, (int)(NE / 8));
    const int wn8 = (int)(WE / 8);                     // 131072
    cast_w4<<<dim3(wn8 / 256, 4), 256, 0, stream>>>(
        Wq, Wk, Wv, Wo, W3b, W3b + WE, W3b + 2 * WE, Wob, wn8);

    // fused QKV projection: [M,3C] = xb @ W3^T
    gemm_bt_mfma<true><<<dim3(QKV_LD / BN, M / BM), 256, 0, stream>>>(
        xb, W3b, QKVb, M, QKV_LD, C_DIM, 1.0f);

    // V transpose to [B*NH, HS, T]
    transpose_v<<<dim3(T_DIM / 64, B_DIM * NHEAD), 256, 0, stream>>>(
        QKVb + 2 * C_DIM, Vtb, QKV_LD);

    // attention (8 waves, QSUB=2, 256 q-rows per block)
    attn_mfma4<<<dim3(T_DIM / 256, B_DIM * NHEAD), 512, 0, stream>>>(
        QKVb, QKVb + C_DIM, Vtb, Ob);

    // output projection (fp32 out)
    gemm_bt_mfma<false><<<dim3(C_DIM / BN, M / BM), 256, 0, stream>>>(
        Ob, Wob, out, M, C_DIM, C_DIM, 1.0f);
}